// Round 10
// baseline (205.625 us; speedup 1.0000x reference)
//
#include <hip/hip_runtime.h>

// Conv1d as implicit GEMM on MFMA bf16 — R14.
// out[n,f,t] = sum_{c,k} x[n,c,t+k] * w[f,c,k] + b[f]
// N=32, C=64, W=4096, F=128, WW=64, out_W=4033. Output fp32.
//
// R14 = R12's barrier-free body at 2x occupancy (4 waves/SIMD).
//  * Diagnosis: VGPR=128 + LDS 33 KB -> HW holds 4 blocks/CU, but grid
//    512 = exactly 2/CU. Half the wave slots empty (Occupancy ~18%).
//    R11-R13's software pipelining was compensating for missing TLP.
//  * F-split across blocks: grid (16 tb x 2 fh) x 32 n = 1024 blocks =
//    4 blocks/CU. Block = 256t x 64f; wave = 64t x 64f -> acc[4][4] =
//    64 regs. Forced-live ~124 <= 128: fits 4-wave budget with NO
//    cross-body prefetch — TLP hides B/L2 and LDS latency (m114).
//  * Body: 8 B loads at top (tap1's L2 latency covered by tap0's 16-MFMA
//    pass), two 4-stage rolling-A passes; compiler CSEs tap1 re-reads
//    (~5 ds_reads/body). No sched_barrier (CSE wanted), runtime-loop
//    back-edge dam (R12 lesson) controls liveness.
//  * fh-pair blocks share the x window; Δbid=16 ≡ 0 mod 8 -> same XCD,
//    x re-fetch L2-absorbed. w frag layout / prep unchanged.
//  * R6's split failed on the BARRIERED structure (phase overheads did
//    not shrink) + launch_bounds spills; barrier-free costs halve with
//    the tile, and acc-halving frees the registers.

#define C_TOT    64
#define F_TOT    128
#define KW       64
#define OUT_W    4033
#define W_IN     4096
#define N_BATCH  32
#define T_BLK    256
#define XROWS    320
#define XSTR     40            // xt row stride (shorts) = 80 B
#define TRS      260           // epilogue transpose row stride (dwords)

typedef __attribute__((ext_vector_type(8))) short  short8;
typedef __attribute__((ext_vector_type(4))) float  floatx4;

__device__ inline unsigned short f32_to_bf16(float f) {
  unsigned int u = __float_as_uint(f);
  u += 0x7FFF + ((u >> 16) & 1);
  return (unsigned short)(u >> 16);
}

// ---- prep: w[f][c][k] fp32 -> frag-packed bf16 (unchanged from R12) ----
// frag id = ((gi*2 + tap)*2 + fh2)*4 + ft ; lane = q*16 + col ; elem e 0..7
//   k = (gi&15) + 32*((gi>>4)&1) + 16*tap
//   f = fh2*64 + ft*16 + col
//   c = (gi>>5)*32 + q*8 + e
// short index = frag*512 + lane*8 + e   (total 1 MB, no padding)
__global__ __launch_bounds__(256) void conv1d_prep(
    const float* __restrict__ w, unsigned short* __restrict__ wsw) {
  int j = blockIdx.x * 256 + threadIdx.x;     // 131072 ushort4 jobs
  if (j < 131072) {
    int e4  = (j & 1) * 4;
    int col = (j >> 1) & 15;
    int q   = (j >> 5) & 3;
    int ft  = (j >> 7) & 3;
    int fh2 = (j >> 9) & 1;
    int tap = (j >> 10) & 1;
    int gi  = j >> 11;
    int k   = (gi & 15) + 32 * ((gi >> 4) & 1) + 16 * tap;
    int f   = fh2 * 64 + ft * 16 + col;
    int c0  = (gi >> 5) * 32 + q * 8 + e4;
    const float* src = w + ((size_t)f * C_TOT + c0) * KW + k;
    ushort4 o;
    o.x = f32_to_bf16(src[0 * KW]);
    o.y = f32_to_bf16(src[1 * KW]);
    o.z = f32_to_bf16(src[2 * KW]);
    o.w = f32_to_bf16(src[3 * KW]);
    *(ushort4*)&wsw[(size_t)j * 4] = o;
  }
}

// ---------------- main GEMM ----------------
__global__ __launch_bounds__(256, 4) void conv1d_mfma(
    const float* __restrict__ x, const unsigned short* __restrict__ wsw,
    const float* __restrict__ b, float* __restrict__ out) {
  __shared__ union SM {
    unsigned short xt[XROWS * XSTR];   // 25.6 KB  x tile bf16 [t][c-half]
    float tr[16 * TRS];                // 16.6 KB  epilogue overlay
  } sm;

  const int tid  = threadIdx.x;
  const int lane = tid & 63;
  const int q    = lane >> 4;    // 0..3
  const int col  = lane & 15;
  const int tq   = tid >> 6;     // wave = t-quarter (64 t each)
  const int n    = blockIdx.y;
  const int bx   = blockIdx.x;   // bits0..3 = t-block, bit4 = f-half
  const int t0   = (bx & 15) * T_BLK;
  const int fh   = bx >> 4;      // this block's f half (64 f)

  const float* xrowb = x + (size_t)n * C_TOT * W_IN;
  // per-thread w pointer: frag(gi,tap,ft) = wp[gi*1024 + tap*512 + ft*64]
  const short8* wp = (const short8*)wsw + fh * 256 + lane;

  floatx4 acc[4][4];             // [ms][ft]
#pragma unroll
  for (int ms = 0; ms < 4; ++ms)
#pragma unroll
    for (int ft = 0; ft < 4; ++ft) acc[ms][ft] = (floatx4)0.0f;

  // x stage for one c-half: c-strided dword loads -> ushort4 writes
#define STAGE_X(hc_)                                                           \
  {                                                                            \
    _Pragma("unroll")                                                          \
    for (int r = 0; r < 10; ++r) {                                             \
      int ti = (r % 5) * 64 + (tid & 63);                                      \
      int cl = ((r / 5) * 4 + (tid >> 6)) * 4;                                 \
      int gt = t0 + ti;                                                        \
      const float* src = xrowb + (size_t)((hc_) * 32 + cl) * W_IN + gt;        \
      float4 v = {0.f, 0.f, 0.f, 0.f};                                         \
      if (gt < W_IN) {                                                         \
        v.x = src[0];                                                          \
        v.y = src[W_IN];                                                       \
        v.z = src[2 * W_IN];                                                   \
        v.w = src[3 * W_IN];                                                   \
      }                                                                        \
      ushort4 o;                                                               \
      o.x = f32_to_bf16(v.x); o.y = f32_to_bf16(v.y);                          \
      o.z = f32_to_bf16(v.z); o.w = f32_to_bf16(v.w);                          \
      *(ushort4*)&sm.xt[ti * XSTR + cl] = o;                                   \
    }                                                                          \
  }

  STAGE_X(0)
  __syncthreads();

  for (int gi = 0; gi < 64; ++gi) {
    const int k1 = (gi & 15) + 32 * ((gi >> 4) & 1);   // taps (k1, k1+16)
    const unsigned short* ap = &sm.xt[(64 * tq + col + k1) * XSTR + q * 8];

    // 8 B loads up top; Bt0 used after ~2 ds_reads, Bt1 after 16 MFMAs.
    short8 Bt0[4], Bt1[4];
#pragma unroll
    for (int ft = 0; ft < 4; ++ft) {
      Bt0[ft] = wp[ft * 64];
      Bt1[ft] = wp[512 + ft * 64];
    }

    // ---- tap0 pass: A[0..3], rolling 3-slot window ----
    short8 As[3];
    As[0] = *(const short8*)&ap[0];
    As[1] = *(const short8*)&ap[1 * 16 * XSTR];
    __builtin_amdgcn_s_setprio(1);
#pragma unroll
    for (int ms = 0; ms < 4; ++ms) {
      if (ms < 2)                      // A[ms+2] -> slot (ms+2)%3
        As[(ms + 2) % 3] = *(const short8*)&ap[(ms + 2) * 16 * XSTR];
#pragma unroll
      for (int ft = 0; ft < 4; ++ft)
        acc[ms][ft] = __builtin_amdgcn_mfma_f32_16x16x32_bf16(
            As[ms % 3], Bt0[ft], acc[ms][ft], 0, 0, 0);
    }
    // ---- tap1 pass: A[1..4]; A1/A2/A3 CSE with tap0's reads ----
    short8 Az[3];
    Az[1] = *(const short8*)&ap[1 * 16 * XSTR];
    Az[2] = *(const short8*)&ap[2 * 16 * XSTR];
#pragma unroll
    for (int ms = 0; ms < 4; ++ms) {
      if (ms < 2)                      // A[ms+3] -> slot ms%3
        Az[ms % 3] = *(const short8*)&ap[(ms + 3) * 16 * XSTR];
#pragma unroll
      for (int ft = 0; ft < 4; ++ft)
        acc[ms][ft] = __builtin_amdgcn_mfma_f32_16x16x32_bf16(
            Az[(ms + 1) % 3], Bt1[ft], acc[ms][ft], 0, 0, 0);
    }
    __builtin_amdgcn_s_setprio(0);

    wp += 1024;

    if (gi == 31) {              // c-half switch (xt readers all done)
      __syncthreads();
      STAGE_X(1)
      __syncthreads();
    }
  }
  __syncthreads();               // waves may drift: resync before tr overlay

  // ---- epilogue: LDS transpose to [f][t], coalesced float4 stores ----
  // D layout: t_loc = 64*tq + 16*ms + 4*q + r, f = 64*fh + 16*ft + col
  const int fs_r  = tid >> 4;           // f-slot for reads (0..15)
  const int seg   = tid & 15;
  const size_t ob = ((size_t)n * F_TOT) * OUT_W;

#pragma unroll
  for (int j = 0; j < 4; ++j) {         // round j handles ft == j (COMPILE-TIME)
#pragma unroll
    for (int ms = 0; ms < 4; ++ms) {
      float4 vv;
      vv.x = acc[ms][j][0];
      vv.y = acc[ms][j][1];
      vv.z = acc[ms][j][2];
      vv.w = acc[ms][j][3];
      int tl = 64 * tq + 16 * ms + 4 * q;
      *(float4*)&sm.tr[col * TRS + tl] = vv;
    }
    __syncthreads();
    const int f = fh * 64 + j * 16 + fs_r;
    const float bias = b[f];
    const size_t obf = ob + (size_t)f * OUT_W;
#pragma unroll
    for (int j2 = 0; j2 < 4; ++j2) {
      int tl = seg * 4 + 64 * j2;
      float4 vv = *(const float4*)&sm.tr[fs_r * TRS + tl];
      vv.x += bias; vv.y += bias; vv.z += bias; vv.w += bias;
      int t = t0 + tl;
      if (t + 3 < OUT_W) {
        *(float4*)&out[obf + t] = vv;
      } else {
        float e[4] = {vv.x, vv.y, vv.z, vv.w};
#pragma unroll
        for (int u = 0; u < 4; ++u)
          if (t + u < OUT_W) out[obf + t + u] = e[u];
      }
    }
    __syncthreads();
  }
}

extern "C" void kernel_launch(void* const* d_in, const int* in_sizes, int n_in,
                              void* d_out, int out_size, void* d_ws, size_t ws_size,
                              hipStream_t stream) {
  const float* x = (const float*)d_in[0];
  const float* w = (const float*)d_in[1];
  const float* b = (const float*)d_in[2];
  float* out = (float*)d_out;

  unsigned short* wsw = (unsigned short*)d_ws;   // 1 MB frag-packed bf16 w

  conv1d_prep<<<512, 256, 0, stream>>>(w, wsw);

  dim3 grid(32, N_BATCH);  // (16 t-blocks x 2 f-halves) x 32 = 1024 blocks
  conv1d_mfma<<<grid, 256, 0, stream>>>(x, wsw, b, out);
}